// Round 1
// baseline (1110.556 us; speedup 1.0000x reference)
//
#include <hip/hip_runtime.h>

// ---- problem constants ----
constexpr int B_ = 8, T_ = 2048, C_ = 1024, H_ = 16, N_ = 64;
constexpr int M_ = B_ * T_;              // 16384 rows
constexpr int FC_ = 4 * C_;              // 4096

typedef __attribute__((ext_vector_type(8))) short bf16x8;
typedef __attribute__((ext_vector_type(4))) float f32x4;
typedef unsigned short ushort_t;
typedef unsigned int uint_t;

// ---- bf16 <-> f32 helpers (raw ushort storage; avoids union-of-class issues) ----
__device__ __forceinline__ float bfu2f(ushort_t u) {
    union { uint_t i; float f; } c; c.i = ((uint_t)u) << 16; return c.f;
}
__device__ __forceinline__ ushort_t f2bfu(float f) {
    union { float f; uint_t i; } c; c.f = f;
    uint_t i = c.i;
    uint_t r = i + 0x7FFFu + ((i >> 16) & 1u);   // round-to-nearest-even
    return (ushort_t)(r >> 16);
}

// ---- async global->LDS, 16B per lane (lds dest: wave-uniform base + lane*16) ----
__device__ __forceinline__ void gl_lds16(const void* g, void* l) {
    __builtin_amdgcn_global_load_lds(
        (const __attribute__((address_space(1))) void*)g,
        (__attribute__((address_space(3))) void*)l, 16, 0, 0);
}

// =====================================================================
// fp32 -> bf16 convert (weights). n must be divisible by 1024.
// =====================================================================
__global__ __launch_bounds__(256) void f2bf_kernel(const float* __restrict__ in,
                                                   ushort_t* __restrict__ out) {
    size_t i = ((size_t)blockIdx.x * 256 + threadIdx.x) * 4;
    float4 v = *(const float4*)(in + i);
    uint2 o;
    o.x = (uint_t)f2bfu(v.x) | ((uint_t)f2bfu(v.y) << 16);
    o.y = (uint_t)f2bfu(v.z) | ((uint_t)f2bfu(v.w) << 16);
    *(uint2*)(out + i) = o;
}

// =====================================================================
// LayerNorm over C=1024, one block per row, output bf16
// =====================================================================
__global__ __launch_bounds__(256) void ln_kernel(const float* __restrict__ x,
                                                 const float* __restrict__ w,
                                                 const float* __restrict__ b,
                                                 ushort_t* __restrict__ out) {
    const int row = blockIdx.x;
    const int tid = threadIdx.x;
    const float* xr = x + (size_t)row * C_;
    float4 xv = ((const float4*)xr)[tid];
    float s  = xv.x + xv.y + xv.z + xv.w;
    float ss = xv.x*xv.x + xv.y*xv.y + xv.z*xv.z + xv.w*xv.w;
#pragma unroll
    for (int off = 32; off; off >>= 1) { s += __shfl_down(s, off); ss += __shfl_down(ss, off); }
    __shared__ float sb[8];
    const int wv = tid >> 6, ln = tid & 63;
    if (ln == 0) { sb[wv] = s; sb[4 + wv] = ss; }
    __syncthreads();
    s  = sb[0] + sb[1] + sb[2] + sb[3];
    ss = sb[4] + sb[5] + sb[6] + sb[7];
    const float mean = s * (1.f / C_);
    const float var  = ss * (1.f / C_) - mean * mean;
    const float rstd = rsqrtf(var + 1e-5f);
    float4 wv4 = ((const float4*)w)[tid];
    float4 bv4 = ((const float4*)b)[tid];
    uint2 o;
    o.x = (uint_t)f2bfu((xv.x - mean) * rstd * wv4.x + bv4.x)
        | ((uint_t)f2bfu((xv.y - mean) * rstd * wv4.y + bv4.y) << 16);
    o.y = (uint_t)f2bfu((xv.z - mean) * rstd * wv4.z + bv4.z)
        | ((uint_t)f2bfu((xv.w - mean) * rstd * wv4.w + bv4.w) << 16);
    ((uint2*)(out + (size_t)row * C_))[tid] = o;
}

// =====================================================================
// shift kernels: hs[b,t] = h[b,t-1] (0 at t=0); optional xx = hs - h
// 8 bf16 per thread (16B vectors)
// =====================================================================
__global__ __launch_bounds__(256) void shift_xx_kernel(const ushort_t* __restrict__ h,
                                                       ushort_t* __restrict__ hs,
                                                       ushort_t* __restrict__ xx) {
    size_t e = ((size_t)blockIdx.x * 256 + threadIdx.x) * 8;
    size_t m = e >> 10;              // /C
    int t = (int)(m & (T_ - 1));     // %T (T=2048 pow2)
    uint4 cu = *(const uint4*)(h + e);
    uint4 pu = make_uint4(0u, 0u, 0u, 0u);
    if (t > 0) pu = *(const uint4*)(h + e - C_);
    *(uint4*)(hs + e) = pu;
    const uint_t pc[4] = {pu.x, pu.y, pu.z, pu.w};
    const uint_t cc[4] = {cu.x, cu.y, cu.z, cu.w};
    uint_t oc[4];
#pragma unroll
    for (int j = 0; j < 4; ++j) {
        float p0 = bfu2f((ushort_t)(pc[j] & 0xffffu)), p1 = bfu2f((ushort_t)(pc[j] >> 16));
        float c0 = bfu2f((ushort_t)(cc[j] & 0xffffu)), c1 = bfu2f((ushort_t)(cc[j] >> 16));
        oc[j] = (uint_t)f2bfu(p0 - c0) | ((uint_t)f2bfu(p1 - c1) << 16);
    }
    *(uint4*)(xx + e) = make_uint4(oc[0], oc[1], oc[2], oc[3]);
}

__global__ __launch_bounds__(256) void shift_kernel(const ushort_t* __restrict__ h,
                                                    ushort_t* __restrict__ hs) {
    size_t e = ((size_t)blockIdx.x * 256 + threadIdx.x) * 8;
    size_t m = e >> 10;
    int t = (int)(m & (T_ - 1));
    uint4 pu = make_uint4(0u, 0u, 0u, 0u);
    if (t > 0) pu = *(const uint4*)(h + e - C_);
    *(uint4*)(hs + e) = pu;
}

// =====================================================================
// gate[m,h] = sigmoid(dot(xx[m,:], w_g[h,:])) ; one block per row
// =====================================================================
__global__ __launch_bounds__(256) void gate_kernel(const ushort_t* __restrict__ xx,
                                                   const float* __restrict__ wg,
                                                   float* __restrict__ gate) {
    __shared__ float xr[C_];
    const int row = blockIdx.x;
    const int tid = threadIdx.x;
    uint2 p = *(const uint2*)(xx + (size_t)row * C_ + tid * 4);
    xr[tid * 4 + 0] = bfu2f((ushort_t)(p.x & 0xffffu));
    xr[tid * 4 + 1] = bfu2f((ushort_t)(p.x >> 16));
    xr[tid * 4 + 2] = bfu2f((ushort_t)(p.y & 0xffffu));
    xr[tid * 4 + 3] = bfu2f((ushort_t)(p.y >> 16));
    __syncthreads();
    const int wv = tid >> 6, ln = tid & 63;
#pragma unroll
    for (int hh = 0; hh < 4; ++hh) {
        const int h = wv * 4 + hh;
        const float* wrow = wg + (size_t)h * C_;
        float acc = 0.f;
#pragma unroll
        for (int i = 0; i < 16; ++i) { int c = i * 64 + ln; acc += xr[c] * wrow[c]; }
#pragma unroll
        for (int off = 32; off; off >>= 1) acc += __shfl_down(acc, off);
        if (ln == 0) gate[(size_t)row * H_ + h] = 1.f / (1.f + __expf(-acc));
    }
}

// =====================================================================
// wkv fwd+bwd scan (decay 0.5) with 32-step warmup windows, fused combine:
// xc = r * (g*fwd + (1-g)*bwd), bf16 out. Block = (b, h, chunk of 128 t).
// =====================================================================
__global__ __launch_bounds__(128) void wkv_combine_kernel(const float* __restrict__ v,
                                                          const ushort_t* __restrict__ r,
                                                          const float* __restrict__ gate,
                                                          ushort_t* __restrict__ xc) {
    __shared__ float fbuf[128 * 64];
    __shared__ float bbuf[128 * 64];
    const int blk = blockIdx.x;           // b*256 + h*16 + chunk
    const int chunk = blk & 15;
    const int bh = blk >> 4;
    const int h = bh & 15;
    const int b = bh >> 4;
    const int t0 = chunk * 128, t1 = t0 + 128;
    const int tid = threadIdx.x;
    const int n = tid & 63;
    const float* vb = v + (size_t)b * T_ * C_ + h * 64 + n;
    if (tid < 64) {                       // wave 0: forward
        int ts = t0 - 32; if (ts < 0) ts = 0;
        float carry = vb[(size_t)ts * C_];
        if (ts >= t0) fbuf[(ts - t0) * 64 + n] = carry;   // only chunk 0: out[0]=v[0]
        for (int t = ts + 1; t < t1; ++t) {
            carry = 0.5f * (carry + vb[(size_t)t * C_]);
            if (t >= t0) fbuf[(t - t0) * 64 + n] = carry;
        }
    } else {                              // wave 1: backward
        int ts = t1 - 1 + 32; if (ts > T_ - 1) ts = T_ - 1;
        float carry = vb[(size_t)ts * C_];
        if (ts < t1) bbuf[(ts - t0) * 64 + n] = carry;    // only last chunk: bwd[T-1]=v[T-1]
        for (int t = ts - 1; t >= t0; --t) {
            carry = 0.5f * (carry + vb[(size_t)t * C_]);
            if (t < t1) bbuf[(t - t0) * 64 + n] = carry;
        }
    }
    __syncthreads();
#pragma unroll 4
    for (int i = 0; i < 64; ++i) {
        int idx = i * 128 + tid;
        int tl = idx >> 6, nn = idx & 63;
        size_t mrow = (size_t)b * T_ + (t0 + tl);
        float g = gate[mrow * H_ + h];
        float rr = bfu2f(r[mrow * C_ + h * 64 + nn]);
        float val = rr * (g * fbuf[tl * 64 + nn] + (1.f - g) * bbuf[tl * 64 + nn]);
        xc[mrow * C_ + h * 64 + nn] = f2bfu(val);
    }
}

// =====================================================================
// bf16 GEMM: C[M,N] = A[M,K] * B[N,K]^T  (both K-contiguous), m97 structure:
// 128x128 tile, BK=32, 4 waves, 4x4 16x16x32 MFMA per wave, global_load_lds x16B.
// EPI: 0 = store bf16; 1 = store f32; 2 = store f32 (extra+acc); 3 = relu^2 bf16
// =====================================================================
template <int EPI>
__global__ __launch_bounds__(256) void gemm_bt(const ushort_t* __restrict__ A,
                                               const ushort_t* __restrict__ Bm,
                                               const float* __restrict__ extra,
                                               float* __restrict__ outF,
                                               ushort_t* __restrict__ outB,
                                               int M, int N, int K) {
    __shared__ ushort_t As[128 * 32];
    __shared__ ushort_t Bs[128 * 32];
    const int tid = threadIdx.x;
    const int lane = tid & 63, wv = tid >> 6;
    const size_t m0 = (size_t)blockIdx.y * 128;
    const size_t n0 = (size_t)blockIdx.x * 128;

    // staging: per round, wave wv covers rows [round*64 + wv*16, +16), lane -> (row,col8)
    const int srow = wv * 16 + (lane >> 2);
    const int scol = (lane & 3) * 8;
    const ushort_t* Ag = A + (m0 + srow) * (size_t)K + scol;
    const ushort_t* Bg = Bm + (n0 + srow) * (size_t)K + scol;
    const size_t rstep = (size_t)64 * K;
    ushort_t* AsW = As + wv * 16 * 32;   // wave-uniform LDS dest
    ushort_t* BsW = Bs + wv * 16 * 32;

    const int wrow = (wv >> 1) * 64, wcol = (wv & 1) * 64;
    const int a_off = (wrow + (lane & 15)) * 32 + (lane >> 4) * 8;
    const int b_off = (wcol + (lane & 15)) * 32 + (lane >> 4) * 8;

    f32x4 acc[4][4];
#pragma unroll
    for (int i = 0; i < 4; ++i)
#pragma unroll
        for (int j = 0; j < 4; ++j) acc[i][j] = (f32x4){0.f, 0.f, 0.f, 0.f};

    for (int k0 = 0; k0 < K; k0 += 32) {
        gl_lds16(Ag + k0,         AsW);
        gl_lds16(Ag + rstep + k0, AsW + 64 * 32);
        gl_lds16(Bg + k0,         BsW);
        gl_lds16(Bg + rstep + k0, BsW + 64 * 32);
        __syncthreads();   // drains vmcnt: staging visible to all
        bf16x8 af[4], bf[4];
#pragma unroll
        for (int i = 0; i < 4; ++i) af[i] = *(const bf16x8*)(const void*)(As + a_off + i * 16 * 32);
#pragma unroll
        for (int i = 0; i < 4; ++i) bf[i] = *(const bf16x8*)(const void*)(Bs + b_off + i * 16 * 32);
#pragma unroll
        for (int mi = 0; mi < 4; ++mi)
#pragma unroll
            for (int ni = 0; ni < 4; ++ni)
                acc[mi][ni] = __builtin_amdgcn_mfma_f32_16x16x32_bf16(af[mi], bf[ni], acc[mi][ni], 0, 0, 0);
        __syncthreads();   // protect LDS from next-iter overwrite
    }

    // epilogue: C/D layout col=lane&15, row=(lane>>4)*4+reg
    const int crow = wrow + (lane >> 4) * 4;
    const int ccol = wcol + (lane & 15);
#pragma unroll
    for (int mi = 0; mi < 4; ++mi) {
#pragma unroll
        for (int ni = 0; ni < 4; ++ni) {
#pragma unroll
            for (int rr = 0; rr < 4; ++rr) {
                size_t row = m0 + crow + mi * 16 + rr;
                size_t col = n0 + ccol + ni * 16;
                size_t oix = row * (size_t)N + col;
                float v = acc[mi][ni][rr];
                if (EPI == 0)      outB[oix] = f2bfu(v);
                else if (EPI == 1) outF[oix] = v;
                else if (EPI == 2) outF[oix] = extra[oix] + v;
                else { float t = v > 0.f ? v : 0.f; outB[oix] = f2bfu(t * t); }
            }
        }
    }
}

// =====================================================================
// launcher
// =====================================================================
extern "C" void kernel_launch(void* const* d_in, const int* in_sizes, int n_in,
                              void* d_out, int out_size, void* d_ws, size_t ws_size,
                              hipStream_t stream) {
    const float* x    = (const float*)d_in[0];
    const float* ln1w = (const float*)d_in[2];
    const float* ln1b = (const float*)d_in[3];
    const float* ln2w = (const float*)d_in[4];
    const float* ln2b = (const float*)d_in[5];
    const float* w_r  = (const float*)d_in[6];
    // d_in[7] = w_k: unused by the reference's _wkv — skipped.
    const float* w_v  = (const float*)d_in[8];
    const float* w_o  = (const float*)d_in[9];
    const float* w_g  = (const float*)d_in[10];
    const float* ck_w = (const float*)d_in[11];
    const float* cv_w = (const float*)d_in[12];

    float* out0 = (float*)d_out;                       // x1 + ffn_out  [M,C]
    float* vout = out0 + (size_t)M_ * C_;              // v_first_out   [M,C] fp32

    char* ws = (char*)d_ws;
    const size_t MB = 1024ull * 1024ull;
    ushort_t* wr_bf = (ushort_t*)(ws + 0 * MB);        // 2MB
    ushort_t* wv_bf = (ushort_t*)(ws + 2 * MB);        // 2MB
    ushort_t* wo_bf = (ushort_t*)(ws + 4 * MB);        // 2MB
    ushort_t* ck_bf = (ushort_t*)(ws + 6 * MB);        // 8MB
    ushort_t* cv_bf = (ushort_t*)(ws + 14 * MB);       // 8MB
    float*    gate  = (float*)(ws + 22 * MB);          // 1MB
    ushort_t* bufA  = (ushort_t*)(ws + 24 * MB);       // 32MB  h1, later h2
    ushort_t* bufB  = (ushort_t*)(ws + 56 * MB);       // 32MB  hs, later h2s
    ushort_t* bufC  = (ushort_t*)(ws + 88 * MB);       // 32MB  xx, later x_comb
    ushort_t* r_bf  = (ushort_t*)(ws + 120 * MB);      // 32MB
    float*    x1    = (float*)(ws + 152 * MB);         // 64MB
    ushort_t* k2p   = (ushort_t*)(ws + 216 * MB);      // 128MB; total 344MB

    // weights fp32 -> bf16
    f2bf_kernel<<<C_ * C_ / 1024, 256, 0, stream>>>(w_r, wr_bf);
    f2bf_kernel<<<C_ * C_ / 1024, 256, 0, stream>>>(w_v, wv_bf);
    f2bf_kernel<<<C_ * C_ / 1024, 256, 0, stream>>>(w_o, wo_bf);
    f2bf_kernel<<<FC_ * C_ / 1024, 256, 0, stream>>>(ck_w, ck_bf);
    f2bf_kernel<<<FC_ * C_ / 1024, 256, 0, stream>>>(cv_w, cv_bf);

    // h = LN1(x); hs = shift(h); xx = hs - h
    ln_kernel<<<M_, 256, 0, stream>>>(x, ln1w, ln1b, bufA);
    shift_xx_kernel<<<(size_t)M_ * C_ / 2048, 256, 0, stream>>>(bufA, bufB, bufC);

    // r = hs @ w_r^T (bf16); v = hs @ w_v^T (fp32, = output 1)
    gemm_bt<0><<<dim3(C_ / 128, M_ / 128), 256, 0, stream>>>(bufB, wr_bf, nullptr, nullptr, r_bf, M_, C_, C_);
    gemm_bt<1><<<dim3(C_ / 128, M_ / 128), 256, 0, stream>>>(bufB, wv_bf, nullptr, vout, nullptr, M_, C_, C_);

    // gate = sigmoid(xx @ w_g^T)
    gate_kernel<<<M_, 256, 0, stream>>>(bufC, w_g, gate);

    // wkv fwd+bwd + combine -> x_comb (bf16, reuses xx buffer)
    wkv_combine_kernel<<<B_ * H_ * (T_ / 128), 128, 0, stream>>>(vout, r_bf, gate, bufC);

    // x1 = x + x_comb @ w_o^T
    gemm_bt<2><<<dim3(C_ / 128, M_ / 128), 256, 0, stream>>>(bufC, wo_bf, x, x1, nullptr, M_, C_, C_);

    // h2 = LN2(x1); h2s = shift(h2)
    ln_kernel<<<M_, 256, 0, stream>>>(x1, ln2w, ln2b, bufA);
    shift_kernel<<<(size_t)M_ * C_ / 2048, 256, 0, stream>>>(bufA, bufB);

    // k2p = relu(h2s @ ck_w^T)^2 (bf16); out0 = x1 + k2p @ cv_w^T
    gemm_bt<3><<<dim3(FC_ / 128, M_ / 128), 256, 0, stream>>>(bufB, ck_bf, nullptr, nullptr, k2p, M_, FC_, C_);
    gemm_bt<2><<<dim3(C_ / 128, M_ / 128), 256, 0, stream>>>(k2p, cv_bf, x1, out0, nullptr, M_, C_, FC_);
}

// Round 2
// 929.472 us; speedup vs baseline: 1.1948x; 1.1948x over previous
//
#include <hip/hip_runtime.h>

// ---- problem constants ----
constexpr int B_ = 8, T_ = 2048, C_ = 1024, H_ = 16, N_ = 64;
constexpr int M_ = B_ * T_;              // 16384 rows
constexpr int FC_ = 4 * C_;              // 4096

typedef __attribute__((ext_vector_type(8))) short bf16x8;
typedef __attribute__((ext_vector_type(4))) float f32x4;
typedef unsigned short ushort_t;
typedef unsigned int uint_t;

__device__ __forceinline__ float bfu2f(ushort_t u) {
    union { uint_t i; float f; } c; c.i = ((uint_t)u) << 16; return c.f;
}
__device__ __forceinline__ ushort_t f2bfu(float f) {
    union { float f; uint_t i; } c; c.f = f;
    uint_t i = c.i;
    uint_t r = i + 0x7FFFu + ((i >> 16) & 1u);   // round-to-nearest-even
    return (ushort_t)(r >> 16);
}

__device__ __forceinline__ void gl_lds16(const void* g, void* l) {
    __builtin_amdgcn_global_load_lds(
        (const __attribute__((address_space(1))) void*)g,
        (__attribute__((address_space(3))) void*)l, 16, 0, 0);
}

// =====================================================================
// fp32 -> bf16 weight converts, folded into 2 launches
// =====================================================================
__global__ __launch_bounds__(256) void f2bf3_kernel(const float* __restrict__ a,
                                                    const float* __restrict__ b,
                                                    const float* __restrict__ c,
                                                    ushort_t* __restrict__ oa,
                                                    ushort_t* __restrict__ ob,
                                                    ushort_t* __restrict__ oc) {
    const float* in = (blockIdx.y == 0) ? a : (blockIdx.y == 1) ? b : c;
    ushort_t* out   = (blockIdx.y == 0) ? oa : (blockIdx.y == 1) ? ob : oc;
    size_t i = ((size_t)blockIdx.x * 256 + threadIdx.x) * 4;
    float4 v = *(const float4*)(in + i);
    uint2 o;
    o.x = (uint_t)f2bfu(v.x) | ((uint_t)f2bfu(v.y) << 16);
    o.y = (uint_t)f2bfu(v.z) | ((uint_t)f2bfu(v.w) << 16);
    *(uint2*)(out + i) = o;
}

__global__ __launch_bounds__(256) void f2bf2_kernel(const float* __restrict__ a,
                                                    const float* __restrict__ b,
                                                    ushort_t* __restrict__ oa,
                                                    ushort_t* __restrict__ ob) {
    const float* in = (blockIdx.y == 0) ? a : b;
    ushort_t* out   = (blockIdx.y == 0) ? oa : ob;
    size_t i = ((size_t)blockIdx.x * 256 + threadIdx.x) * 4;
    float4 v = *(const float4*)(in + i);
    uint2 o;
    o.x = (uint_t)f2bfu(v.x) | ((uint_t)f2bfu(v.y) << 16);
    o.y = (uint_t)f2bfu(v.z) | ((uint_t)f2bfu(v.w) << 16);
    *(uint2*)(out + i) = o;
}

// =====================================================================
// LayerNorm over C=1024, one block per row, output bf16
// =====================================================================
__global__ __launch_bounds__(256) void ln_kernel(const float* __restrict__ x,
                                                 const float* __restrict__ w,
                                                 const float* __restrict__ b,
                                                 ushort_t* __restrict__ out) {
    const int row = blockIdx.x;
    const int tid = threadIdx.x;
    const float* xr = x + (size_t)row * C_;
    float4 xv = ((const float4*)xr)[tid];
    float s  = xv.x + xv.y + xv.z + xv.w;
    float ss = xv.x*xv.x + xv.y*xv.y + xv.z*xv.z + xv.w*xv.w;
#pragma unroll
    for (int off = 32; off; off >>= 1) { s += __shfl_down(s, off); ss += __shfl_down(ss, off); }
    __shared__ float sb[8];
    const int wv = tid >> 6, ln = tid & 63;
    if (ln == 0) { sb[wv] = s; sb[4 + wv] = ss; }
    __syncthreads();
    s  = sb[0] + sb[1] + sb[2] + sb[3];
    ss = sb[4] + sb[5] + sb[6] + sb[7];
    const float mean = s * (1.f / C_);
    const float var  = ss * (1.f / C_) - mean * mean;
    const float rstd = rsqrtf(var + 1e-5f);
    float4 wv4 = ((const float4*)w)[tid];
    float4 bv4 = ((const float4*)b)[tid];
    uint2 o;
    o.x = (uint_t)f2bfu((xv.x - mean) * rstd * wv4.x + bv4.x)
        | ((uint_t)f2bfu((xv.y - mean) * rstd * wv4.y + bv4.y) << 16);
    o.y = (uint_t)f2bfu((xv.z - mean) * rstd * wv4.z + bv4.z)
        | ((uint_t)f2bfu((xv.w - mean) * rstd * wv4.w + bv4.w) << 16);
    ((uint2*)(out + (size_t)row * C_))[tid] = o;
}

// =====================================================================
// gate[m,h] = sigmoid(dot(xx[m,:], w_g[h,:])), xx computed inline:
// xx[t] = h[t-1] - h[t]  (h[t-1]=0 at t==0). One block per row.
// =====================================================================
__global__ __launch_bounds__(256) void gate_kernel(const ushort_t* __restrict__ h,
                                                   const float* __restrict__ wg,
                                                   float* __restrict__ gate) {
    __shared__ float xr[C_];
    const int row = blockIdx.x;
    const int tid = threadIdx.x;
    const int t = row & (T_ - 1);
    uint2 cu = *(const uint2*)(h + (size_t)row * C_ + tid * 4);
    uint2 pu = make_uint2(0u, 0u);
    if (t > 0) pu = *(const uint2*)(h + (size_t)(row - 1) * C_ + tid * 4);
    xr[tid * 4 + 0] = bfu2f((ushort_t)(pu.x & 0xffffu)) - bfu2f((ushort_t)(cu.x & 0xffffu));
    xr[tid * 4 + 1] = bfu2f((ushort_t)(pu.x >> 16))     - bfu2f((ushort_t)(cu.x >> 16));
    xr[tid * 4 + 2] = bfu2f((ushort_t)(pu.y & 0xffffu)) - bfu2f((ushort_t)(cu.y & 0xffffu));
    xr[tid * 4 + 3] = bfu2f((ushort_t)(pu.y >> 16))     - bfu2f((ushort_t)(cu.y >> 16));
    __syncthreads();
    const int wv = tid >> 6, ln = tid & 63;
#pragma unroll
    for (int hh = 0; hh < 4; ++hh) {
        const int h_ = wv * 4 + hh;
        const float* wrow = wg + (size_t)h_ * C_;
        float acc = 0.f;
#pragma unroll
        for (int i = 0; i < 16; ++i) { int c = i * 64 + ln; acc += xr[c] * wrow[c]; }
#pragma unroll
        for (int off = 32; off; off >>= 1) acc += __shfl_down(acc, off);
        if (ln == 0) gate[(size_t)row * H_ + h_] = 1.f / (1.f + __expf(-acc));
    }
}

// =====================================================================
// wkv fwd+bwd scan (decay 0.5) with 32-step warmup windows, fused combine:
// xc = r * (g*fwd + (1-g)*bwd), bf16 out. Block = (b, h, chunk of 128 t).
// =====================================================================
__global__ __launch_bounds__(128) void wkv_combine_kernel(const float* __restrict__ v,
                                                          const ushort_t* __restrict__ r,
                                                          const float* __restrict__ gate,
                                                          ushort_t* __restrict__ xc) {
    __shared__ float fbuf[128 * 64];
    __shared__ float bbuf[128 * 64];
    const int blk = blockIdx.x;           // b*256 + h*16 + chunk
    const int chunk = blk & 15;
    const int bh = blk >> 4;
    const int h = bh & 15;
    const int b = bh >> 4;
    const int t0 = chunk * 128, t1 = t0 + 128;
    const int tid = threadIdx.x;
    const int n = tid & 63;
    const float* vb = v + (size_t)b * T_ * C_ + h * 64 + n;
    if (tid < 64) {                       // wave 0: forward
        int ts = t0 - 32; if (ts < 0) ts = 0;
        float carry = vb[(size_t)ts * C_];
        if (ts >= t0) fbuf[(ts - t0) * 64 + n] = carry;   // only chunk 0: out[0]=v[0]
        for (int t = ts + 1; t < t1; ++t) {
            carry = 0.5f * (carry + vb[(size_t)t * C_]);
            if (t >= t0) fbuf[(t - t0) * 64 + n] = carry;
        }
    } else {                              // wave 1: backward
        int ts = t1 - 1 + 32; if (ts > T_ - 1) ts = T_ - 1;
        float carry = vb[(size_t)ts * C_];
        if (ts < t1) bbuf[(ts - t0) * 64 + n] = carry;    // only last chunk: bwd[T-1]=v[T-1]
        for (int t = ts - 1; t >= t0; --t) {
            carry = 0.5f * (carry + vb[(size_t)t * C_]);
            if (t < t1) bbuf[(t - t0) * 64 + n] = carry;
        }
    }
    __syncthreads();
#pragma unroll 4
    for (int i = 0; i < 64; ++i) {
        int idx = i * 128 + tid;
        int tl = idx >> 6, nn = idx & 63;
        size_t mrow = (size_t)b * T_ + (t0 + tl);
        float g = gate[mrow * H_ + h];
        float rr = bfu2f(r[mrow * C_ + h * 64 + nn]);
        float val = rr * (g * fbuf[tl * 64 + nn] + (1.f - g) * bbuf[tl * 64 + nn]);
        xc[mrow * C_ + h * 64 + nn] = f2bfu(val);
    }
}

// =====================================================================
// bf16 GEMM: C[M,N] = A[M,K] * B[N,K]^T, 256x128 tile, BK=32, 8 waves,
// each wave 4x4 of 16x16x32 MFMA, global_load_lds x16B, grouped raster.
// SHIFT: A row m reads row m-1 (t==0 rows -> zero page)  [fused time-shift]
// EPI: 0 = store bf16; 1 = store f32; 2 = store f32 (extra+acc); 3 = relu^2 bf16
// =====================================================================
template <int EPI, bool SHIFT>
__global__ __launch_bounds__(512, 4) void gemm_bt(const ushort_t* __restrict__ A,
                                                  const ushort_t* __restrict__ Bm,
                                                  const float* __restrict__ extra,
                                                  float* __restrict__ outF,
                                                  ushort_t* __restrict__ outB,
                                                  const ushort_t* __restrict__ zpage,
                                                  int Nb, int N, int K) {
    __shared__ ushort_t As[256 * 32];   // 16 KB
    __shared__ ushort_t Bs[128 * 32];   //  8 KB
    const int tid = threadIdx.x;
    const int lane = tid & 63, wv = tid >> 6;

    // grouped rasterization: GM=8 m-slabs per n-sweep
    const int GM = 8;
    const int per = GM * Nb;
    const int grp = blockIdx.x / per, rem = blockIdx.x % per;
    const size_t m0 = (size_t)(grp * GM + (rem & (GM - 1))) * 256;
    const size_t n0 = (size_t)(rem / GM) * 128;

    // staging: wave wv loads A rows [wv*16,+16) and [128+wv*16,+16), B rows [wv*16,+16)
    const int srow = lane >> 2;          // 0..15
    const int scol = (lane & 3) * 8;
    const size_t ra0 = m0 + wv * 16 + srow;
    const size_t ra1 = ra0 + 128;
    const ushort_t* Abase0;
    const ushort_t* Abase1;
    if (SHIFT) {
        Abase0 = ((ra0 & (T_ - 1)) == 0) ? (zpage + scol) : (A + (ra0 - 1) * (size_t)K + scol);
        Abase1 = ((ra1 & (T_ - 1)) == 0) ? (zpage + scol) : (A + (ra1 - 1) * (size_t)K + scol);
    } else {
        Abase0 = A + ra0 * (size_t)K + scol;
        Abase1 = A + ra1 * (size_t)K + scol;
    }
    const ushort_t* Bbase = Bm + (n0 + wv * 16 + srow) * (size_t)K + scol;
    ushort_t* AsW0 = As + wv * 16 * 32;          // wave-uniform LDS dests
    ushort_t* AsW1 = AsW0 + 128 * 32;
    ushort_t* BsW  = Bs + wv * 16 * 32;

    const int wrow = (wv >> 1) * 64, wcol = (wv & 1) * 64;
    const int a_off = (wrow + (lane & 15)) * 32 + (lane >> 4) * 8;
    const int b_off = (wcol + (lane & 15)) * 32 + (lane >> 4) * 8;

    f32x4 acc[4][4];
#pragma unroll
    for (int i = 0; i < 4; ++i)
#pragma unroll
        for (int j = 0; j < 4; ++j) acc[i][j] = (f32x4){0.f, 0.f, 0.f, 0.f};

    for (int k0 = 0; k0 < K; k0 += 32) {
        gl_lds16(Abase0 + k0, AsW0);
        gl_lds16(Abase1 + k0, AsW1);
        gl_lds16(Bbase  + k0, BsW);
        __syncthreads();   // drains vmcnt: staging visible to all
        bf16x8 af[4], bf[4];
#pragma unroll
        for (int i = 0; i < 4; ++i) af[i] = *(const bf16x8*)(const void*)(As + a_off + i * 16 * 32);
#pragma unroll
        for (int i = 0; i < 4; ++i) bf[i] = *(const bf16x8*)(const void*)(Bs + b_off + i * 16 * 32);
#pragma unroll
        for (int mi = 0; mi < 4; ++mi)
#pragma unroll
            for (int ni = 0; ni < 4; ++ni)
                acc[mi][ni] = __builtin_amdgcn_mfma_f32_16x16x32_bf16(af[mi], bf[ni], acc[mi][ni], 0, 0, 0);
        __syncthreads();   // protect LDS from next-iter overwrite
    }

    // epilogue: C/D layout col=lane&15, row=(lane>>4)*4+reg
    const int crow = wrow + (lane >> 4) * 4;
    const int ccol = wcol + (lane & 15);
#pragma unroll
    for (int mi = 0; mi < 4; ++mi) {
#pragma unroll
        for (int ni = 0; ni < 4; ++ni) {
#pragma unroll
            for (int rr = 0; rr < 4; ++rr) {
                size_t row = m0 + crow + mi * 16 + rr;
                size_t col = n0 + ccol + ni * 16;
                size_t oix = row * (size_t)N + col;
                float v = acc[mi][ni][rr];
                if (EPI == 0)      outB[oix] = f2bfu(v);
                else if (EPI == 1) outF[oix] = v;
                else if (EPI == 2) outF[oix] = extra[oix] + v;
                else { float t = v > 0.f ? v : 0.f; outB[oix] = f2bfu(t * t); }
            }
        }
    }
}

// =====================================================================
// launcher
// =====================================================================
extern "C" void kernel_launch(void* const* d_in, const int* in_sizes, int n_in,
                              void* d_out, int out_size, void* d_ws, size_t ws_size,
                              hipStream_t stream) {
    const float* x    = (const float*)d_in[0];
    const float* ln1w = (const float*)d_in[2];
    const float* ln1b = (const float*)d_in[3];
    const float* ln2w = (const float*)d_in[4];
    const float* ln2b = (const float*)d_in[5];
    const float* w_r  = (const float*)d_in[6];
    // d_in[7] = w_k: unused by the reference's _wkv — skipped.
    const float* w_v  = (const float*)d_in[8];
    const float* w_o  = (const float*)d_in[9];
    const float* w_g  = (const float*)d_in[10];
    const float* ck_w = (const float*)d_in[11];
    const float* cv_w = (const float*)d_in[12];

    float* out0 = (float*)d_out;                       // x1 + ffn_out  [M,C]
    float* vout = out0 + (size_t)M_ * C_;              // v_first_out   [M,C] fp32

    char* ws = (char*)d_ws;
    const size_t MB = 1024ull * 1024ull;
    ushort_t* wr_bf = (ushort_t*)(ws + 0 * MB);        // 2MB
    ushort_t* wv_bf = (ushort_t*)(ws + 2 * MB);        // 2MB
    ushort_t* wo_bf = (ushort_t*)(ws + 4 * MB);        // 2MB
    ushort_t* ck_bf = (ushort_t*)(ws + 6 * MB);        // 8MB
    ushort_t* cv_bf = (ushort_t*)(ws + 14 * MB);       // 8MB
    float*    gate  = (float*)(ws + 22 * MB);          // 1MB
    ushort_t* zpage = (ushort_t*)(ws + 23 * MB);       // 4KB (1MB slot)
    ushort_t* bufA  = (ushort_t*)(ws + 24 * MB);       // 32MB  h1, later h2
    ushort_t* bufC  = (ushort_t*)(ws + 56 * MB);       // 32MB  x_comb
    ushort_t* r_bf  = (ushort_t*)(ws + 88 * MB);       // 32MB
    float*    x1    = (float*)(ws + 120 * MB);         // 64MB
    ushort_t* k2p   = (ushort_t*)(ws + 184 * MB);      // 128MB; total 312MB

    // weights fp32 -> bf16 (2 launches); zero page for shifted GEMM rows
    f2bf3_kernel<<<dim3(C_ * C_ / 1024, 3), 256, 0, stream>>>(w_r, w_v, w_o, wr_bf, wv_bf, wo_bf);
    f2bf2_kernel<<<dim3(FC_ * C_ / 1024, 2), 256, 0, stream>>>(ck_w, cv_w, ck_bf, cv_bf);
    hipMemsetAsync(zpage, 0, 4096, stream);

    // h = LN1(x)
    ln_kernel<<<M_, 256, 0, stream>>>(x, ln1w, ln1b, bufA);

    // gate = sigmoid((shift(h)-h) @ w_g^T), shift computed inline
    gate_kernel<<<M_, 256, 0, stream>>>(bufA, w_g, gate);

    // r = shift(h) @ w_r^T (bf16); v = shift(h) @ w_v^T (fp32, = output 1)
    gemm_bt<0, true><<<(M_ / 256) * (C_ / 128), 512, 0, stream>>>(bufA, wr_bf, nullptr, nullptr, r_bf, zpage, C_ / 128, C_, C_);
    gemm_bt<1, true><<<(M_ / 256) * (C_ / 128), 512, 0, stream>>>(bufA, wv_bf, nullptr, vout, nullptr, zpage, C_ / 128, C_, C_);

    // wkv fwd+bwd + combine -> x_comb
    wkv_combine_kernel<<<B_ * H_ * (T_ / 128), 128, 0, stream>>>(vout, r_bf, gate, bufC);

    // x1 = x + x_comb @ w_o^T
    gemm_bt<2, false><<<(M_ / 256) * (C_ / 128), 512, 0, stream>>>(bufC, wo_bf, x, x1, nullptr, zpage, C_ / 128, C_, C_);

    // h2 = LN2(x1)
    ln_kernel<<<M_, 256, 0, stream>>>(x1, ln2w, ln2b, bufA);

    // k2p = relu(shift(h2) @ ck_w^T)^2 (bf16, shift fused); out0 = x1 + k2p @ cv_w^T
    gemm_bt<3, true><<<(M_ / 256) * (FC_ / 128), 512, 0, stream>>>(bufA, ck_bf, nullptr, nullptr, k2p, zpage, FC_ / 128, FC_, C_);
    gemm_bt<2, false><<<(M_ / 256) * (C_ / 128), 512, 0, stream>>>(k2p, cv_bf, x1, out0, nullptr, zpage, C_ / 128, C_, FC_);
}